// Round 10
// baseline (123.814 us; speedup 1.0000x reference)
//
#include <hip/hip_runtime.h>

// B=8, Cin=64, H=W=128, Cout=64, 9 bilinear taps at (i+0.4, j+0.4).
// v13: SEPARABLE FACTORIZATION. All taps share fractional offset 0.4 ->
//   bilinear gather = (vertical blur V: xv[u] = 0.6 x[u] + 0.4 x[u+1], folded
//   into staging) o (horizontal part folded into weights). Effective kernel
//   becomes 3x4: out = sum_{i=0..2,s=0..3} W34[i][s] * xv[oy-1+i][ox-1+s],
//   W34[i][s] = 0.6*w[.,.,(i,s)] + 0.4*w[.,.,(i,s-1)]. Exact (pad rows are
//   zero, so the reference's index clamping is equivalent to zero-extension).
//   - MFMA count -25% (12 rs vs 16), wb2 stream 128->96 KB (-25% of the
//     dominant L2 stream per v10's ledger), LDS row writes 4->3 per pass.
//   - Base structure = v10 (best, 106.66): single wave/block, barrier-free
//     2-slot LDS ring, 2048 blocks x 64 thr, strip = 1 row x 64 px x 64 Cout.
//     6 phases (2 ch passes x 3 xv rows); blur = 2 VALU/elem during staging.
//   - Numerics: not bitwise-identical to v10 (blurred x rounded to bf16,
//     refolded weights); expected absmax same order as 0.015625.

#define CIN   64
#define COUT  64
#define HH    128
#define WW    128

typedef __attribute__((ext_vector_type(8))) short bf16x8;   // 8 bf16 = 4 VGPRs
typedef __attribute__((ext_vector_type(4))) float f32x4;
typedef __attribute__((ext_vector_type(4))) unsigned int u32x4;

__device__ __forceinline__ unsigned short f2bf(float f) {
  unsigned int u = __float_as_uint(f);
  u = (u + 0x7fffu + ((u >> 16) & 1u)) >> 16;   // RNE
  return (unsigned short)u;
}

__device__ __forceinline__ unsigned int cvtpk(float lo, float hi) {
  unsigned int r;                                // D = {bf16(lo), bf16(hi)} RNE
  asm("v_cvt_pk_bf16_f32 %0, %1, %2" : "=v"(r) : "v"(lo), "v"(hi));
  return r;
}

// ---------------------------------------------------------------------------
// W34[o][c][i][s] = sum_k w[o,c,k] * [s==ix_k]*(1-fx_k) + [s==ix_k+1]*fx_k,
// for tap-row i = iy_k. Vertical fraction fy goes into the image blur.
// Stream layout: wb2[(((p*12+rs)*4 + n)*64 + lane)*8 + j], rs = i*4+s;
// consuming lane l holds o = n*16+(l&15), ch = p*32+(l>>4)*8+j. (layout
// verified by the v3..v12 lineage)
// ---------------------------------------------------------------------------
__global__ void make_wb(const float* __restrict__ wgt,
                        const float* __restrict__ off,
                        unsigned short* __restrict__ wb2)
{
  int id = blockIdx.x * 64 + threadIdx.x;       // 4096 = 64*64
  int o = id >> 6, c = id & 63;
  float W12[12];
  #pragma unroll
  for (int i = 0; i < 12; ++i) W12[i] = 0.f;
  for (int k = 0; k < 9; ++k) {
    float dy = off[2*k], dx = off[2*k+1];
    int   iy = (int)floorf(dy);                 // 0..2
    int   ix = (int)floorf(dx);                 // 0..2
    float fx = dx - floorf(dx);
    float wk = wgt[(o*CIN + c)*9 + k];
    W12[iy*4 + ix    ] += wk * (1.f - fx);
    W12[iy*4 + ix + 1] += wk * fx;
  }
  int p = c >> 5, q = (c >> 3) & 3, j = c & 7;
  int n = o >> 4, m15 = o & 15;
  int lanei = q*16 + m15;
  for (int rs = 0; rs < 12; ++rs)
    wb2[(size_t)(((p*12 + rs)*4 + n)*64 + lanei)*8 + j] = f2bf(W12[rs]);
}

// ---------------------------------------------------------------------------
// conv: 1 wave per block, strip = 1 out row x 64 px x 64 Cout, no barriers.
// LDS ring: slot = 68 cols x 4 chunk-slots x 16 B = 4352 B, XOR swizzle.
// 6 phases: pass p in {0,1} x blurred row r in {0,1,2}.
// ---------------------------------------------------------------------------
__global__ __launch_bounds__(64, 2)   // VGPR cap 256 (est ~205 used)
void conv_mfma(const float* __restrict__ x,
               const float* __restrict__ off,
               const unsigned short* __restrict__ wb2,
               float* __restrict__ out)
{
  __shared__ __align__(16) char lds[17408];     // ring 2x4352 B; epi f32[64][68]

  const int wg  = blockIdx.x;                   // 2048
  const int xcd = wg & 7;
  const int i   = wg >> 3;                      // 0..255
  const int b   = i >> 5;                       // 0..7
  const int r5  = i & 31;
  const int y0  = xcd * 16 + (r5 >> 1);         // XCD-local 16-row band
  const int x0  = (r5 & 1) * 64;                // x half
  const int lane = threadIdx.x;                 // 0..63
  const int m15  = lane & 15;
  const int q    = lane >> 4;

  // vertical blur coefficients (all taps share the fractional offset)
  const float dy0 = off[0];
  const float cy1 = dy0 - floorf(dy0);          // 0.4
  const float cy0 = 1.f - cy1;                  // 0.6

  // ---- per-lane staging constants (v10) ----
  int gx   = x0 - 1 + lane;                     // main col = lane
  bool gxv = ((unsigned)gx < (unsigned)WW);
  int gxc  = gx < 0 ? 0 : (gx > WW-1 ? WW-1 : gx);
  const int he = (lane >> 4) < 3 ? (lane >> 4) : 2;   // halo col 64+he
  int gxh  = x0 + 63 + he;
  bool gxhv = ((unsigned)gxh < (unsigned)WW) && (lane < 48);
  int gxhc = gxh > WW-1 ? WW-1 : gxh;
  const int hp = lane & 15;                     // halo ch-pair: ch = 2hp, 2hp+1
  const int hoff = (64 + he)*64 + ((hp >> 2) & 3)*16 + (hp & 3)*4;

  int stoff[4];
  #pragma unroll
  for (int c = 0; c < 4; ++c)
    stoff[c] = lane*64 + ((c + (lane >> 2)) & 3)*16;

  int aoff[4];
  #pragma unroll
  for (int s = 0; s < 4; ++s) {
    int c0 = m15 + s;
    aoff[s] = c0*64 + ((q + (c0 >> 2)) & 3)*16;
  }

  f32x4 acc[4][4];
  #pragma unroll
  for (int mi = 0; mi < 4; ++mi)
    #pragma unroll
    for (int nn = 0; nn < 4; ++nn)
      acc[mi][nn] = (f32x4){0.f, 0.f, 0.f, 0.f};

  float GA[32], GB[32], HA[2], HB[2];           // named x-row double buffer

  // load x row gy (channels [32p,32p+32)) into GM/GH; zeros if OOB (blur input)
  auto LOADX = [&](int gy, int p, float* GM, float* GH) {
    if ((unsigned)gy < (unsigned)HH) {
      const float* ps = x + ((size_t)((b*CIN + p*32)*HH + gy))*WW;
      #pragma unroll
      for (int cc = 0; cc < 32; ++cc) GM[cc] = ps[(size_t)cc*HH*WW + gxc];
      GH[0] = ps[(size_t)(2*hp    )*HH*WW + gxhc];
      GH[1] = ps[(size_t)(2*hp + 1)*HH*WW + gxhc];
    } else {
      #pragma unroll
      for (int cc = 0; cc < 32; ++cc) GM[cc] = 0.f;
      GH[0] = 0.f; GH[1] = 0.f;
    }
  };

  // write blurred row xv = cy0*A + cy1*B into ring slot
  auto WRITEV = [&](int slot, const float* A, const float* B,
                    const float* XA, const float* XB) {
    char* base = lds + slot*4352;
    #pragma unroll
    for (int c = 0; c < 4; ++c) {
      unsigned int pk[4];
      #pragma unroll
      for (int w = 0; w < 4; ++w) {
        float lo = cy0*A[c*8 + 2*w    ] + cy1*B[c*8 + 2*w    ];
        float hi = cy0*A[c*8 + 2*w + 1] + cy1*B[c*8 + 2*w + 1];
        pk[w] = cvtpk(lo, hi);
        pk[w] = gxv ? pk[w] : 0u;               // zero-pad cols gx==-1/128/129
      }
      *(u32x4*)(base + stoff[c]) = *(u32x4*)pk;
    }
    unsigned int hw = cvtpk(cy0*XA[0] + cy1*XB[0], cy0*XA[1] + cy1*XB[1]);
    hw = gxhv ? hw : 0u;
    if (lane < 48) *(unsigned int*)(base + hoff) = hw;
  };

  // COMPUTE(k): pass = k/3, blurred row r = k%3, ring slot k&1; 12 rs total.
  auto COMPUTE = [&](int k) {
    const int r = k % 3;
    const char* ab = lds + (k & 1)*4352;
    const char* wb = (const char*)wb2 + (size_t)(k / 3)*49152 + (size_t)lane*16;
    #pragma unroll
    for (int s = 0; s < 4; ++s) {
      bf16x8 afr[4];
      #pragma unroll
      for (int mi = 0; mi < 4; ++mi)
        afr[mi] = *(const bf16x8*)(ab + aoff[s] + mi*1024);
      const char* w0 = wb + (size_t)(r*4 + s)*4096;
      bf16x8 bfr[4];
      #pragma unroll
      for (int n = 0; n < 4; ++n)
        bfr[n] = *(const bf16x8*)(w0 + n*1024);
      #pragma unroll
      for (int mi = 0; mi < 4; ++mi)
        #pragma unroll
        for (int nn = 0; nn < 4; ++nn)
          acc[mi][nn] = __builtin_amdgcn_mfma_f32_16x16x32_bf16(afr[mi], bfr[nn], acc[mi][nn], 0, 0, 0);
    }
  };

  // ---- pipeline, 6 phases, no barriers (single-wave in-order LDS) ----
  // x rows R0..R3 = gy y0-1 .. y0+2; xv_r = cy0*R(r) + cy1*R(r+1).
  LOADX(y0 - 1, 0, GA, HA);                     // R0
  LOADX(y0,     0, GB, HB);                     // R1
  WRITEV(0, GA, GB, HA, HB);                    // xv0
  LOADX(y0 + 1, 0, GA, HA);                     // R2
  COMPUTE(0);
  WRITEV(1, GB, GA, HB, HA);                    // xv1
  LOADX(y0 + 2, 0, GB, HB);                     // R3
  COMPUTE(1);
  WRITEV(0, GA, GB, HA, HB);                    // xv2
  LOADX(y0 - 1, 1, GA, HA);                     // pass-1 R0
  COMPUTE(2);
  LOADX(y0,     1, GB, HB);                     // pass-1 R1
  WRITEV(1, GA, GB, HA, HB);
  LOADX(y0 + 1, 1, GA, HA);
  COMPUTE(3);
  WRITEV(0, GB, GA, HB, HA);
  LOADX(y0 + 2, 1, GB, HB);
  COMPUTE(4);
  WRITEV(1, GA, GB, HA, HB);
  COMPUTE(5);

  // ---- epilogue: transpose through LDS (single wave), coalesced stores ----
  float* epi = (float*)lds;
  #pragma unroll
  for (int mi = 0; mi < 4; ++mi)
    #pragma unroll
    for (int nn = 0; nn < 4; ++nn) {
      int o  = nn*16 + m15;
      int px = mi*16 + q*4;                     // D row = q*4 + reg
      *(f32x4*)&epi[o*68 + px] = acc[mi][nn];
    }
  #pragma unroll
  for (int i2 = 0; i2 < 16; ++i2) {
    int o  = i2*4 + q;
    int px = m15*4;
    f32x4 v = *(const f32x4*)&epi[o*68 + px];
    *(f32x4*)&out[(((size_t)(b*COUT + o))*HH + y0)*WW + x0 + px] = v;
  }
}

// ---------------------------------------------------------------------------
extern "C" void kernel_launch(void* const* d_in, const int* in_sizes, int n_in,
                              void* d_out, int out_size, void* d_ws, size_t ws_size,
                              hipStream_t stream)
{
  const float* x   = (const float*)d_in[0];   // [8,64,128,128] fp32
  const float* wgt = (const float*)d_in[1];   // [64,64,9] fp32
  const float* off = (const float*)d_in[2];   // [9,2] fp32
  float* out = (float*)d_out;                 // [8,64,128,128] fp32
  unsigned short* wb2 = (unsigned short*)d_ws;// 96 KB stream-layout weights

  make_wb<<<64, 64, 0, stream>>>(wgt, off, wb2);
  conv_mfma<<<2048, 64, 0, stream>>>(x, off, wb2, out);
}

// Round 12
// 110.099 us; speedup vs baseline: 1.1246x; 1.1246x over previous
//
#include <hip/hip_runtime.h>

// B=8, Cin=64, H=W=128, Cout=64, 9 bilinear taps at (i+0.4, j+0.4).
// v14 (resubmit; R11 failure was infra: "container failed twice", no kernel
//      signal): separable 3x4 factorization (v13, numerically verified) with
//      the register-spill fixed.
//   - v13 post-mortem: spill (~45 MB scratch traffic, VGPR capped at 128).
//     Causes: two full x-row buffers live cross-phase + rename spike;
//     launch_bounds(64,2) empirically caps arch VGPR at 128; float*-param
//     lambdas defeat SROA of staging arrays.
//   - v14 fixes: (1) prescale form: persistent S = cy0*prev_row, single T
//     arrival buffer; blur = fma(cy1, T, S); then S := cy0*T. 64 x-regs max.
//     (2) macros on named arrays, compile-time indices only (rule #20).
//     (3) __launch_bounds__(64,1): VGPR cap 512, honest ~200 alloc, no spill,
//     still 2 waves/SIMD via natural allocation (LDS allows 8 blocks/CU).
//   - Everything else = v13: 12 rs (-25% MFMA), wb2 96 KB (-25% L2 stream),
//     barrier-free single-wave 2-slot LDS ring, 2048 blocks x 64 thr.

#define CIN   64
#define COUT  64
#define HH    128
#define WW    128

typedef __attribute__((ext_vector_type(8))) short bf16x8;   // 8 bf16 = 4 VGPRs
typedef __attribute__((ext_vector_type(4))) float f32x4;
typedef __attribute__((ext_vector_type(4))) unsigned int u32x4;

__device__ __forceinline__ unsigned short f2bf(float f) {
  unsigned int u = __float_as_uint(f);
  u = (u + 0x7fffu + ((u >> 16) & 1u)) >> 16;   // RNE
  return (unsigned short)u;
}

__device__ __forceinline__ unsigned int cvtpk(float lo, float hi) {
  unsigned int r;                                // D = {bf16(lo), bf16(hi)} RNE
  asm("v_cvt_pk_bf16_f32 %0, %1, %2" : "=v"(r) : "v"(lo), "v"(hi));
  return r;
}

// ---------------------------------------------------------------------------
// W34 fold: horizontal bilinear into weights, vertical fraction into the image
// blur. wb2[(((p*12+rs)*4 + n)*64 + lane)*8 + j], rs = i*4+s. (v13-verified)
// ---------------------------------------------------------------------------
__global__ void make_wb(const float* __restrict__ wgt,
                        const float* __restrict__ off,
                        unsigned short* __restrict__ wb2)
{
  int id = blockIdx.x * 64 + threadIdx.x;       // 4096 = 64*64
  int o = id >> 6, c = id & 63;
  float W12[12];
  #pragma unroll
  for (int i = 0; i < 12; ++i) W12[i] = 0.f;
  for (int k = 0; k < 9; ++k) {
    float dy = off[2*k], dx = off[2*k+1];
    int   iy = (int)floorf(dy);                 // 0..2
    int   ix = (int)floorf(dx);                 // 0..2
    float fx = dx - floorf(dx);
    float wk = wgt[(o*CIN + c)*9 + k];
    W12[iy*4 + ix    ] += wk * (1.f - fx);
    W12[iy*4 + ix + 1] += wk * fx;
  }
  int p = c >> 5, q = (c >> 3) & 3, j = c & 7;
  int n = o >> 4, m15 = o & 15;
  int lanei = q*16 + m15;
  for (int rs = 0; rs < 12; ++rs)
    wb2[(size_t)(((p*12 + rs)*4 + n)*64 + lanei)*8 + j] = f2bf(W12[rs]);
}

// ---------------------------------------------------------------------------
// conv: 1 wave/block, strip = 1 out row x 64 px x 64 Cout, no barriers.
// LDS ring: slot = 68 cols x 4 chunk-slots x 16 B = 4352 B, XOR swizzle.
// 6 phases: pass p in {0,1} x blurred row r in {0,1,2}.
// ---------------------------------------------------------------------------
__global__ __launch_bounds__(64, 1)   // VGPR cap 512: no forced spill
void conv_mfma(const float* __restrict__ x,
               const float* __restrict__ off,
               const unsigned short* __restrict__ wb2,
               float* __restrict__ out)
{
  __shared__ __align__(16) char lds[17408];     // ring 2x4352 B; epi f32[64][68]

  const int wg  = blockIdx.x;                   // 2048
  const int xcd = wg & 7;
  const int i   = wg >> 3;                      // 0..255
  const int b   = i >> 5;                       // 0..7
  const int r5  = i & 31;
  const int y0  = xcd * 16 + (r5 >> 1);         // XCD-local 16-row band
  const int x0  = (r5 & 1) * 64;                // x half
  const int lane = threadIdx.x;                 // 0..63
  const int m15  = lane & 15;
  const int q    = lane >> 4;

  const float dy0 = off[0];
  const float cy1 = dy0 - floorf(dy0);          // 0.4
  const float cy0 = 1.f - cy1;                  // 0.6

  // ---- per-lane staging constants (v10/v13) ----
  int gx   = x0 - 1 + lane;                     // main col = lane
  bool gxv = ((unsigned)gx < (unsigned)WW);
  int gxc  = gx < 0 ? 0 : (gx > WW-1 ? WW-1 : gx);
  const int he = (lane >> 4) < 3 ? (lane >> 4) : 2;   // halo col 64+he
  int gxh  = x0 + 63 + he;
  bool gxhv = ((unsigned)gxh < (unsigned)WW) && (lane < 48);
  int gxhc = gxh > WW-1 ? WW-1 : gxh;
  const int hp = lane & 15;                     // halo ch-pair: ch = 2hp, 2hp+1
  const int hoff = (64 + he)*64 + ((hp >> 2) & 3)*16 + (hp & 3)*4;

  int stoff[4];
  #pragma unroll
  for (int c = 0; c < 4; ++c)
    stoff[c] = lane*64 + ((c + (lane >> 2)) & 3)*16;

  int aoff[4];
  #pragma unroll
  for (int s = 0; s < 4; ++s) {
    int c0 = m15 + s;
    aoff[s] = c0*64 + ((q + (c0 >> 2)) & 3)*16;
  }

  f32x4 acc[4][4];
  #pragma unroll
  for (int mi = 0; mi < 4; ++mi)
    #pragma unroll
    for (int nn = 0; nn < 4; ++nn)
      acc[mi][nn] = (f32x4){0.f, 0.f, 0.f, 0.f};

  // staging registers: persistent prescaled S, single arrival buffer T
  float S[32], T[32];
  float HS0, HS1, HT0, HT1;

// load x row gy (channels [32p,32p+32)) into T/HT; zeros if OOB
#define LOADT(gy_, p_) do {                                                 \
    int gy = (gy_);                                                         \
    if ((unsigned)gy < (unsigned)HH) {                                      \
      const float* ps = x + ((size_t)((b*CIN + (p_)*32)*HH + gy))*WW;       \
      _Pragma("unroll")                                                     \
      for (int cc = 0; cc < 32; ++cc) T[cc] = ps[(size_t)cc*HH*WW + gxc];   \
      HT0 = ps[(size_t)(2*hp    )*HH*WW + gxhc];                            \
      HT1 = ps[(size_t)(2*hp + 1)*HH*WW + gxhc];                            \
    } else {                                                                \
      _Pragma("unroll")                                                     \
      for (int cc = 0; cc < 32; ++cc) T[cc] = 0.f;                          \
      HT0 = 0.f; HT1 = 0.f;                                                 \
    }                                                                       \
  } while (0)

// S := cy0 * T (fold arrived row into prescaled form)
#define SETS() do {                                                         \
    _Pragma("unroll")                                                       \
    for (int cc = 0; cc < 32; ++cc) S[cc] = cy0 * T[cc];                    \
    HS0 = cy0 * HT0; HS1 = cy0 * HT1;                                       \
  } while (0)

// write blurred row xv = S + cy1*T to ring slot, then S := cy0*T
#define BLURW(slot_) do {                                                   \
    char* base = lds + (slot_)*4352;                                        \
    _Pragma("unroll")                                                       \
    for (int c = 0; c < 4; ++c) {                                           \
      unsigned int pk[4];                                                   \
      _Pragma("unroll")                                                     \
      for (int w = 0; w < 4; ++w) {                                         \
        float lo = S[c*8 + 2*w    ] + cy1 * T[c*8 + 2*w    ];               \
        float hi = S[c*8 + 2*w + 1] + cy1 * T[c*8 + 2*w + 1];               \
        pk[w] = cvtpk(lo, hi);                                              \
        pk[w] = gxv ? pk[w] : 0u;                                           \
      }                                                                     \
      *(u32x4*)(base + stoff[c]) = *(u32x4*)pk;                             \
    }                                                                       \
    unsigned int hw = cvtpk(HS0 + cy1*HT0, HS1 + cy1*HT1);                  \
    hw = gxhv ? hw : 0u;                                                    \
    if (lane < 48) *(unsigned int*)(base + hoff) = hw;                      \
    SETS();                                                                 \
  } while (0)

  // COMPUTE(k): pass = k/3, blurred row r = k%3, ring slot k&1; 12 rs total.
  auto COMPUTE = [&](int k) {
    const int r = k % 3;
    const char* ab = lds + (k & 1)*4352;
    const char* wb = (const char*)wb2 + (size_t)(k / 3)*49152 + (size_t)lane*16;
    #pragma unroll
    for (int s = 0; s < 4; ++s) {
      bf16x8 afr[4];
      #pragma unroll
      for (int mi = 0; mi < 4; ++mi)
        afr[mi] = *(const bf16x8*)(ab + aoff[s] + mi*1024);
      const char* w0 = wb + (size_t)(r*4 + s)*4096;
      bf16x8 bfr[4];
      #pragma unroll
      for (int n = 0; n < 4; ++n)
        bfr[n] = *(const bf16x8*)(w0 + n*1024);
      #pragma unroll
      for (int mi = 0; mi < 4; ++mi)
        #pragma unroll
        for (int nn = 0; nn < 4; ++nn)
          acc[mi][nn] = __builtin_amdgcn_mfma_f32_16x16x32_bf16(afr[mi], bfr[nn], acc[mi][nn], 0, 0, 0);
    }
  };

  // ---- 6-phase barrier-free pipeline ----
  LOADT(y0 - 1, 0); SETS();                     // S = cy0 * R(-1)
  LOADT(y0,     0);
  BLURW(0);                                     // xv0; S = cy0*R0
  LOADT(y0 + 1, 0);
  COMPUTE(0);
  BLURW(1);                                     // xv1; S = cy0*R1
  LOADT(y0 + 2, 0);
  COMPUTE(1);
  BLURW(0);                                     // xv2
  LOADT(y0 - 1, 1);                             // pass-1 row -1 (in flight)
  COMPUTE(2);
  SETS();                                       // S = cy0 * R(-1) pass 1
  LOADT(y0,     1);
  BLURW(1);                                     // xv0'
  LOADT(y0 + 1, 1);
  COMPUTE(3);
  BLURW(0);                                     // xv1'
  LOADT(y0 + 2, 1);
  COMPUTE(4);
  BLURW(1);                                     // xv2'
  COMPUTE(5);

#undef LOADT
#undef SETS
#undef BLURW

  // ---- epilogue: transpose through LDS (single wave), coalesced stores ----
  float* epi = (float*)lds;
  #pragma unroll
  for (int mi = 0; mi < 4; ++mi)
    #pragma unroll
    for (int nn = 0; nn < 4; ++nn) {
      int o  = nn*16 + m15;
      int px = mi*16 + q*4;                     // D row = q*4 + reg
      *(f32x4*)&epi[o*68 + px] = acc[mi][nn];
    }
  #pragma unroll
  for (int i2 = 0; i2 < 16; ++i2) {
    int o  = i2*4 + q;
    int px = m15*4;
    f32x4 v = *(const f32x4*)&epi[o*68 + px];
    *(f32x4*)&out[(((size_t)(b*COUT + o))*HH + y0)*WW + x0 + px] = v;
  }
}

// ---------------------------------------------------------------------------
extern "C" void kernel_launch(void* const* d_in, const int* in_sizes, int n_in,
                              void* d_out, int out_size, void* d_ws, size_t ws_size,
                              hipStream_t stream)
{
  const float* x   = (const float*)d_in[0];   // [8,64,128,128] fp32
  const float* wgt = (const float*)d_in[1];   // [64,64,9] fp32
  const float* off = (const float*)d_in[2];   // [9,2] fp32
  float* out = (float*)d_out;                 // [8,64,128,128] fp32
  unsigned short* wb2 = (unsigned short*)d_ws;// 96 KB stream-layout weights

  make_wb<<<64, 64, 0, stream>>>(wgt, off, wb2);
  conv_mfma<<<2048, 64, 0, stream>>>(x, off, wb2, out);
}

// Round 13
// 101.582 us; speedup vs baseline: 1.2189x; 1.0838x over previous
//
#include <hip/hip_runtime.h>

// B=8, Cin=64, H=W=128, Cout=64, 9 bilinear taps at (i+0.4, j+0.4).
// v15: v14 (separable 3x4, spill-proof staging) + __launch_bounds__(64,2).
//   - v14 post-mortem: no spill, math verified, but (64,1) let the allocator
//     exceed 256 regs -> 1 wave/SIMD -> lost the TLP that covers the
//     barrier-free pipeline's load latency; 110.1 vs v10's 106.66.
//   - v15: (64,2) caps 256 regs/wave. v14's live set (~185: acc 64 + S/T 64
//     + frags 32 + addressing ~25) fits -> no spill (v13's spill cause was
//     the two-full-buffer + lambda structure, already eliminated).
//   - Keeps: 12 rs (-25% MFMA), wb2 96 KB (-25% of the dominant L2 stream),
//     barrier-free single-wave 2-slot LDS ring, 2048 blocks x 64 thr,
//     2 waves/SIMD, 8 blocks/CU.

#define CIN   64
#define COUT  64
#define HH    128
#define WW    128

typedef __attribute__((ext_vector_type(8))) short bf16x8;   // 8 bf16 = 4 VGPRs
typedef __attribute__((ext_vector_type(4))) float f32x4;
typedef __attribute__((ext_vector_type(4))) unsigned int u32x4;

__device__ __forceinline__ unsigned short f2bf(float f) {
  unsigned int u = __float_as_uint(f);
  u = (u + 0x7fffu + ((u >> 16) & 1u)) >> 16;   // RNE
  return (unsigned short)u;
}

__device__ __forceinline__ unsigned int cvtpk(float lo, float hi) {
  unsigned int r;                                // D = {bf16(lo), bf16(hi)} RNE
  asm("v_cvt_pk_bf16_f32 %0, %1, %2" : "=v"(r) : "v"(lo), "v"(hi));
  return r;
}

// ---------------------------------------------------------------------------
// W34 fold: horizontal bilinear into weights, vertical fraction into the image
// blur. wb2[(((p*12+rs)*4 + n)*64 + lane)*8 + j], rs = i*4+s. (v13-verified)
// ---------------------------------------------------------------------------
__global__ void make_wb(const float* __restrict__ wgt,
                        const float* __restrict__ off,
                        unsigned short* __restrict__ wb2)
{
  int id = blockIdx.x * 64 + threadIdx.x;       // 4096 = 64*64
  int o = id >> 6, c = id & 63;
  float W12[12];
  #pragma unroll
  for (int i = 0; i < 12; ++i) W12[i] = 0.f;
  for (int k = 0; k < 9; ++k) {
    float dy = off[2*k], dx = off[2*k+1];
    int   iy = (int)floorf(dy);                 // 0..2
    int   ix = (int)floorf(dx);                 // 0..2
    float fx = dx - floorf(dx);
    float wk = wgt[(o*CIN + c)*9 + k];
    W12[iy*4 + ix    ] += wk * (1.f - fx);
    W12[iy*4 + ix + 1] += wk * fx;
  }
  int p = c >> 5, q = (c >> 3) & 3, j = c & 7;
  int n = o >> 4, m15 = o & 15;
  int lanei = q*16 + m15;
  for (int rs = 0; rs < 12; ++rs)
    wb2[(size_t)(((p*12 + rs)*4 + n)*64 + lanei)*8 + j] = f2bf(W12[rs]);
}

// ---------------------------------------------------------------------------
// conv: 1 wave/block, strip = 1 out row x 64 px x 64 Cout, no barriers.
// LDS ring: slot = 68 cols x 4 chunk-slots x 16 B = 4352 B, XOR swizzle.
// 6 phases: pass p in {0,1} x blurred row r in {0,1,2}.
// ---------------------------------------------------------------------------
__global__ __launch_bounds__(64, 2)   // 256-reg cap: fits (~185), 2 waves/SIMD
void conv_mfma(const float* __restrict__ x,
               const float* __restrict__ off,
               const unsigned short* __restrict__ wb2,
               float* __restrict__ out)
{
  __shared__ __align__(16) char lds[17408];     // ring 2x4352 B; epi f32[64][68]

  const int wg  = blockIdx.x;                   // 2048
  const int xcd = wg & 7;
  const int i   = wg >> 3;                      // 0..255
  const int b   = i >> 5;                       // 0..7
  const int r5  = i & 31;
  const int y0  = xcd * 16 + (r5 >> 1);         // XCD-local 16-row band
  const int x0  = (r5 & 1) * 64;                // x half
  const int lane = threadIdx.x;                 // 0..63
  const int m15  = lane & 15;
  const int q    = lane >> 4;

  const float dy0 = off[0];
  const float cy1 = dy0 - floorf(dy0);          // 0.4
  const float cy0 = 1.f - cy1;                  // 0.6

  // ---- per-lane staging constants (v10/v13) ----
  int gx   = x0 - 1 + lane;                     // main col = lane
  bool gxv = ((unsigned)gx < (unsigned)WW);
  int gxc  = gx < 0 ? 0 : (gx > WW-1 ? WW-1 : gx);
  const int he = (lane >> 4) < 3 ? (lane >> 4) : 2;   // halo col 64+he
  int gxh  = x0 + 63 + he;
  bool gxhv = ((unsigned)gxh < (unsigned)WW) && (lane < 48);
  int gxhc = gxh > WW-1 ? WW-1 : gxh;
  const int hp = lane & 15;                     // halo ch-pair: ch = 2hp, 2hp+1
  const int hoff = (64 + he)*64 + ((hp >> 2) & 3)*16 + (hp & 3)*4;

  int stoff[4];
  #pragma unroll
  for (int c = 0; c < 4; ++c)
    stoff[c] = lane*64 + ((c + (lane >> 2)) & 3)*16;

  int aoff[4];
  #pragma unroll
  for (int s = 0; s < 4; ++s) {
    int c0 = m15 + s;
    aoff[s] = c0*64 + ((q + (c0 >> 2)) & 3)*16;
  }

  f32x4 acc[4][4];
  #pragma unroll
  for (int mi = 0; mi < 4; ++mi)
    #pragma unroll
    for (int nn = 0; nn < 4; ++nn)
      acc[mi][nn] = (f32x4){0.f, 0.f, 0.f, 0.f};

  // staging registers: persistent prescaled S, single arrival buffer T
  float S[32], T[32];
  float HS0, HS1, HT0, HT1;

// load x row gy (channels [32p,32p+32)) into T/HT; zeros if OOB
#define LOADT(gy_, p_) do {                                                 \
    int gy = (gy_);                                                         \
    if ((unsigned)gy < (unsigned)HH) {                                      \
      const float* ps = x + ((size_t)((b*CIN + (p_)*32)*HH + gy))*WW;       \
      _Pragma("unroll")                                                     \
      for (int cc = 0; cc < 32; ++cc) T[cc] = ps[(size_t)cc*HH*WW + gxc];   \
      HT0 = ps[(size_t)(2*hp    )*HH*WW + gxhc];                            \
      HT1 = ps[(size_t)(2*hp + 1)*HH*WW + gxhc];                            \
    } else {                                                                \
      _Pragma("unroll")                                                     \
      for (int cc = 0; cc < 32; ++cc) T[cc] = 0.f;                          \
      HT0 = 0.f; HT1 = 0.f;                                                 \
    }                                                                       \
  } while (0)

// S := cy0 * T (fold arrived row into prescaled form)
#define SETS() do {                                                         \
    _Pragma("unroll")                                                       \
    for (int cc = 0; cc < 32; ++cc) S[cc] = cy0 * T[cc];                    \
    HS0 = cy0 * HT0; HS1 = cy0 * HT1;                                       \
  } while (0)

// write blurred row xv = S + cy1*T to ring slot, then S := cy0*T
#define BLURW(slot_) do {                                                   \
    char* base = lds + (slot_)*4352;                                        \
    _Pragma("unroll")                                                       \
    for (int c = 0; c < 4; ++c) {                                           \
      unsigned int pk[4];                                                   \
      _Pragma("unroll")                                                     \
      for (int w = 0; w < 4; ++w) {                                         \
        float lo = S[c*8 + 2*w    ] + cy1 * T[c*8 + 2*w    ];               \
        float hi = S[c*8 + 2*w + 1] + cy1 * T[c*8 + 2*w + 1];               \
        pk[w] = cvtpk(lo, hi);                                              \
        pk[w] = gxv ? pk[w] : 0u;                                           \
      }                                                                     \
      *(u32x4*)(base + stoff[c]) = *(u32x4*)pk;                             \
    }                                                                       \
    unsigned int hw = cvtpk(HS0 + cy1*HT0, HS1 + cy1*HT1);                  \
    hw = gxhv ? hw : 0u;                                                    \
    if (lane < 48) *(unsigned int*)(base + hoff) = hw;                      \
    SETS();                                                                 \
  } while (0)

  // COMPUTE(k): pass = k/3, blurred row r = k%3, ring slot k&1; 12 rs total.
  auto COMPUTE = [&](int k) {
    const int r = k % 3;
    const char* ab = lds + (k & 1)*4352;
    const char* wb = (const char*)wb2 + (size_t)(k / 3)*49152 + (size_t)lane*16;
    #pragma unroll
    for (int s = 0; s < 4; ++s) {
      bf16x8 afr[4];
      #pragma unroll
      for (int mi = 0; mi < 4; ++mi)
        afr[mi] = *(const bf16x8*)(ab + aoff[s] + mi*1024);
      const char* w0 = wb + (size_t)(r*4 + s)*4096;
      bf16x8 bfr[4];
      #pragma unroll
      for (int n = 0; n < 4; ++n)
        bfr[n] = *(const bf16x8*)(w0 + n*1024);
      #pragma unroll
      for (int mi = 0; mi < 4; ++mi)
        #pragma unroll
        for (int nn = 0; nn < 4; ++nn)
          acc[mi][nn] = __builtin_amdgcn_mfma_f32_16x16x32_bf16(afr[mi], bfr[nn], acc[mi][nn], 0, 0, 0);
    }
  };

  // ---- 6-phase barrier-free pipeline ----
  LOADT(y0 - 1, 0); SETS();                     // S = cy0 * R(-1)
  LOADT(y0,     0);
  BLURW(0);                                     // xv0; S = cy0*R0
  LOADT(y0 + 1, 0);
  COMPUTE(0);
  BLURW(1);                                     // xv1; S = cy0*R1
  LOADT(y0 + 2, 0);
  COMPUTE(1);
  BLURW(0);                                     // xv2
  LOADT(y0 - 1, 1);                             // pass-1 row -1 (in flight)
  COMPUTE(2);
  SETS();                                       // S = cy0 * R(-1) pass 1
  LOADT(y0,     1);
  BLURW(1);                                     // xv0'
  LOADT(y0 + 1, 1);
  COMPUTE(3);
  BLURW(0);                                     // xv1'
  LOADT(y0 + 2, 1);
  COMPUTE(4);
  BLURW(1);                                     // xv2'
  COMPUTE(5);

#undef LOADT
#undef SETS
#undef BLURW

  // ---- epilogue: transpose through LDS (single wave), coalesced stores ----
  float* epi = (float*)lds;
  #pragma unroll
  for (int mi = 0; mi < 4; ++mi)
    #pragma unroll
    for (int nn = 0; nn < 4; ++nn) {
      int o  = nn*16 + m15;
      int px = mi*16 + q*4;                     // D row = q*4 + reg
      *(f32x4*)&epi[o*68 + px] = acc[mi][nn];
    }
  #pragma unroll
  for (int i2 = 0; i2 < 16; ++i2) {
    int o  = i2*4 + q;
    int px = m15*4;
    f32x4 v = *(const f32x4*)&epi[o*68 + px];
    *(f32x4*)&out[(((size_t)(b*COUT + o))*HH + y0)*WW + x0 + px] = v;
  }
}

// ---------------------------------------------------------------------------
extern "C" void kernel_launch(void* const* d_in, const int* in_sizes, int n_in,
                              void* d_out, int out_size, void* d_ws, size_t ws_size,
                              hipStream_t stream)
{
  const float* x   = (const float*)d_in[0];   // [8,64,128,128] fp32
  const float* wgt = (const float*)d_in[1];   // [64,64,9] fp32
  const float* off = (const float*)d_in[2];   // [9,2] fp32
  float* out = (float*)d_out;                 // [8,64,128,128] fp32
  unsigned short* wb2 = (unsigned short*)d_ws;// 96 KB stream-layout weights

  make_wb<<<64, 64, 0, stream>>>(wgt, off, wb2);
  conv_mfma<<<2048, 64, 0, stream>>>(x, off, wb2, out);
}